// Round 1
// baseline (101.310 us; speedup 1.0000x reference)
//
#include <hip/hip_runtime.h>

static constexpr float BIGD = 10000000000.0f;

// Precompute known-point table: (batch, x, y, z) as float4 into d_ws.
// Matches reference op order: (idx*vox + off) + 0.5*vox, all f32, no fma.
__global__ void prep_tab(const int* __restrict__ xind, float4* __restrict__ tab, int m) {
#pragma clang fp contract(off)
    int j = blockIdx.x * blockDim.x + threadIdx.x;
    if (j >= m) return;
    int b  = xind[j * 4 + 0];
    int zi = xind[j * 4 + 1];
    int yi = xind[j * 4 + 2];
    int xi = xind[j * 4 + 3];
    float kx = ((float)xi * 0.05f + 0.1f) + 0.025f;
    float ky = ((float)yi * 0.05f + 0.1f) + 0.025f;
    float kz = ((float)zi * 0.1f  + 0.2f) + 0.05f;
    tab[j] = make_float4((float)b, kx, ky, kz);
}

// Block = 256 threads = 4 waves. Each block owns 64 query points.
// Wave w scans chunk w (m/4 knowns) for all 64 points (lane <-> point).
// Partial top-3 merged in LDS with lexicographic (d, idx) — matches
// jax.lax.top_k's lower-index-first tie rule. Then 4 threads/point gather
// the C features with float4.
template <bool PRE>
__global__ __launch_bounds__(256) void knn3(const float4* __restrict__ tab,
                                            const int* __restrict__ xind,
                                            const float* __restrict__ feats,
                                            const float* __restrict__ pts,
                                            float* __restrict__ out,
                                            int m, int n, int C) {
#pragma clang fp contract(off)
    __shared__ float sd[3 * 256];
    __shared__ int   si[3 * 256];
    __shared__ float sw[3 * 64];
    __shared__ int   sn[3 * 64];

    const int t    = threadIdx.x;
    const int lane = t & 63;
    const int wv   = __builtin_amdgcn_readfirstlane(t >> 6);  // force SGPR -> s_load
    const int p    = blockIdx.x * 64 + lane;

    float ub = 0.f, ux = 0.f, uy = 0.f, uz = 0.f;
    if (p < n) {
        const float4 u = *(const float4*)(pts + (size_t)p * 4);
        ub = u.x; ux = u.y; uy = u.z; uz = u.w;
    }

    const int mchunk = (m + 3) >> 2;
    const int j0 = wv * mchunk;
    const int j1 = min(j0 + mchunk, m);

    float b0 = 3.0e38f, b1 = 3.0e38f, b2 = 3.0e38f;
    int   n0 = 0x7fffffff, n1 = 0x7fffffff, n2 = 0x7fffffff;

#pragma unroll 8
    for (int j = j0; j < j1; ++j) {
        float kb, kx, ky, kz;
        if constexpr (PRE) {
            float4 k = tab[j];          // wave-uniform address -> scalar load
            kb = k.x; kx = k.y; ky = k.z; kz = k.w;
        } else {
            int4 v = ((const int4*)xind)[j];
            kb = (float)v.x;
            kx = ((float)v.w * 0.05f + 0.1f) + 0.025f;
            ky = ((float)v.z * 0.05f + 0.1f) + 0.025f;
            kz = ((float)v.y * 0.1f  + 0.2f) + 0.05f;
        }
        float dx = ux - kx;
        float dy = uy - ky;
        float dz = uz - kz;
        float d = dx * dx + dy * dy;   // contract(off): separate mul/add like np
        d = d + dz * dz;
        d = (ub == kb) ? d : BIGD;
        // branchless top-3 insert; strict < with ascending j == tie keeps lower idx
        bool c2 = d < b2, c1 = d < b1, c0 = d < b0;
        float t2 = c1 ? b1 : (c2 ? d : b2);
        int   u2 = c1 ? n1 : (c2 ? j : n2);
        float t1 = c0 ? b0 : (c1 ? d : b1);
        int   u1 = c0 ? n0 : (c1 ? j : n1);
        b0 = c0 ? d : b0;
        n0 = c0 ? j : n0;
        b1 = t1; n1 = u1; b2 = t2; n2 = u2;
    }

    sd[t * 3 + 0] = b0; sd[t * 3 + 1] = b1; sd[t * 3 + 2] = b2;
    si[t * 3 + 0] = n0; si[t * 3 + 1] = n1; si[t * 3 + 2] = n2;
    __syncthreads();

    if (t < 64) {
        float d0 = sd[t * 3 + 0], d1 = sd[t * 3 + 1], d2 = sd[t * 3 + 2];
        int   i0 = si[t * 3 + 0], i1 = si[t * 3 + 1], i2 = si[t * 3 + 2];
        for (int w = 1; w < 4; ++w) {
            int base = (w * 64 + t) * 3;
            for (int k = 0; k < 3; ++k) {
                float d = sd[base + k];
                int   i = si[base + k];
                bool c2v = (d < d2) || (d == d2 && i < i2);
                bool c1v = (d < d1) || (d == d1 && i < i1);
                bool c0v = (d < d0) || (d == d0 && i < i0);
                float t2 = c1v ? d1 : (c2v ? d : d2);
                int   u2 = c1v ? i1 : (c2v ? i : i2);
                float t1 = c0v ? d0 : (c1v ? d : d1);
                int   u1 = c0v ? i0 : (c1v ? i : i1);
                d0 = c0v ? d : d0; i0 = c0v ? i : i0;
                d1 = t1; i1 = u1; d2 = t2; i2 = u2;
            }
        }
        float r0 = 1.0f / (d0 + 1e-8f);
        float r1 = 1.0f / (d1 + 1e-8f);
        float r2 = 1.0f / (d2 + 1e-8f);
        float s  = r0 + r1 + r2;
        sw[t * 3 + 0] = r0 / s; sw[t * 3 + 1] = r1 / s; sw[t * 3 + 2] = r2 / s;
        sn[t * 3 + 0] = i0;     sn[t * 3 + 1] = i1;     sn[t * 3 + 2] = i2;
    }
    __syncthreads();

    // Epilogue: 4 threads per point gather C features (float4 stride 4).
    const int pl = t >> 2;
    const int q  = t & 3;
    const int pp = blockIdx.x * 64 + pl;
    if (pp < n) {
        float w0 = sw[pl * 3 + 0], w1 = sw[pl * 3 + 1], w2 = sw[pl * 3 + 2];
        const int nf4 = C >> 2;
        const float4* F  = (const float4*)feats;
        const float4* F0 = F + (size_t)sn[pl * 3 + 0] * nf4;
        const float4* F1 = F + (size_t)sn[pl * 3 + 1] * nf4;
        const float4* F2 = F + (size_t)sn[pl * 3 + 2] * nf4;
        float4* O = (float4*)out + (size_t)pp * nf4;
        for (int c = q; c < nf4; c += 4) {
            float4 a = F0[c], b = F1[c], cc = F2[c];
            float4 o;
            o.x = w0 * a.x + w1 * b.x + w2 * cc.x;
            o.y = w0 * a.y + w1 * b.y + w2 * cc.y;
            o.z = w0 * a.z + w1 * b.z + w2 * cc.z;
            o.w = w0 * a.w + w1 * b.w + w2 * cc.w;
            O[c] = o;
        }
    }
}

extern "C" void kernel_launch(void* const* d_in, const int* in_sizes, int n_in,
                              void* d_out, int out_size, void* d_ws, size_t ws_size,
                              hipStream_t stream) {
    const float* feats = (const float*)d_in[0];
    const int*   xind  = (const int*)d_in[1];
    const float* pts   = (const float*)d_in[2];
    float*       out   = (float*)d_out;

    const int m = in_sizes[1] / 4;
    const int n = in_sizes[2] / 4;
    const int C = in_sizes[0] / m;

    const int nb = (n + 63) / 64;

    if (ws_size >= (size_t)m * sizeof(float4)) {
        float4* tab = (float4*)d_ws;
        prep_tab<<<(m + 255) / 256, 256, 0, stream>>>(xind, tab, m);
        knn3<true><<<nb, 256, 0, stream>>>(tab, xind, feats, pts, out, m, n, C);
    } else {
        knn3<false><<<nb, 256, 0, stream>>>(nullptr, xind, feats, pts, out, m, n, C);
    }
}